// Round 9
// baseline (253.621 us; speedup 1.0000x reference)
//
#include <hip/hip_runtime.h>
#include <math.h>

#define BLOCK 256
// Layer cell counts (b=32, 3 anchors):
//  L0: 32*3*13*13 = 16224  -> 64 blocks   (13x13, anchors 6,7,8)
//  L1: 32*3*26*26 = 64896  -> 254 blocks  (26x26, anchors 3,4,5)
//  L2: 32*3*52*52 = 259584 -> 1014 blocks (52x52, anchors 0,1,2)
#define NB0 64
#define NB1 254
#define NB2 1014
#define NBLOCKS (NB0 + NB1 + NB2)

// 4-byte-aligned float4 (only for target loads: 20B stride, L1-resident broadcast)
typedef float f4a __attribute__((ext_vector_type(4), aligned(4)));

// anchors ordered [layer][a]: layer0 = ANCHORS[6,7,8], layer1 = [3,4,5], layer2 = [0,1,2]
__constant__ float c_anch[9][2] = {
    {116.f, 90.f}, {156.f, 198.f}, {373.f, 326.f},
    { 30.f, 61.f}, { 62.f,  45.f}, { 59.f, 119.f},
    { 10.f, 13.f}, { 16.f,  30.f}, { 33.f,  23.f}
};

// stable softplus: log(1+exp(x)) = max(x,0) + log(1+exp(-|x|))
__device__ __forceinline__ float softplusf(float x) {
    float ax = fabsf(x);
    return fmaxf(x, 0.f) + __logf(1.f + __expf(-ax));
}

__device__ __forceinline__ float sigmoidf(float x) {
    return __fdividef(1.f, 1.f + __expf(-x));
}

// ============ inline-asm load pipeline (the compiler-proof MLP path) ============
// R0/R4/R6/R8 all converged ~96-108us: HIP's scheduler re-serializes global
// loads into small batches (VGPR 40-60) and every VMEM round-trip lands on the
// wave's critical path (~130 trips x ~340cy = 44K cy/wave = the measured wall).
// L3-warm replays run at the SAME speed as HBM-cold -> latency-count-bound, not
// BW-bound. Fix per guide §5/T3+T4: asm loads + counted s_waitcnt vmcnt(32),
// which the compiler cannot collapse. 32 loads stay in flight across each phase.

// 16 pred loads: channel stride hw*4 bytes (runtime-uniform, SGPR), lane-coalesced.
__device__ __forceinline__ void issue_pred16(const float* __restrict__ pred,
                                             unsigned voff, unsigned shw4,
                                             float (&x)[16]) {
    asm volatile(
        "global_load_dword %0, %16, %18\n\t"  "v_add_u32 %16, %17, %16\n\t"
        "global_load_dword %1, %16, %18\n\t"  "v_add_u32 %16, %17, %16\n\t"
        "global_load_dword %2, %16, %18\n\t"  "v_add_u32 %16, %17, %16\n\t"
        "global_load_dword %3, %16, %18\n\t"  "v_add_u32 %16, %17, %16\n\t"
        "global_load_dword %4, %16, %18\n\t"  "v_add_u32 %16, %17, %16\n\t"
        "global_load_dword %5, %16, %18\n\t"  "v_add_u32 %16, %17, %16\n\t"
        "global_load_dword %6, %16, %18\n\t"  "v_add_u32 %16, %17, %16\n\t"
        "global_load_dword %7, %16, %18\n\t"  "v_add_u32 %16, %17, %16\n\t"
        "global_load_dword %8, %16, %18\n\t"  "v_add_u32 %16, %17, %16\n\t"
        "global_load_dword %9, %16, %18\n\t"  "v_add_u32 %16, %17, %16\n\t"
        "global_load_dword %10, %16, %18\n\t" "v_add_u32 %16, %17, %16\n\t"
        "global_load_dword %11, %16, %18\n\t" "v_add_u32 %16, %17, %16\n\t"
        "global_load_dword %12, %16, %18\n\t" "v_add_u32 %16, %17, %16\n\t"
        "global_load_dword %13, %16, %18\n\t" "v_add_u32 %16, %17, %16\n\t"
        "global_load_dword %14, %16, %18\n\t" "v_add_u32 %16, %17, %16\n\t"
        "global_load_dword %15, %16, %18"
        : "=v"(x[0]), "=v"(x[1]), "=v"(x[2]), "=v"(x[3]),
          "=v"(x[4]), "=v"(x[5]), "=v"(x[6]), "=v"(x[7]),
          "=v"(x[8]), "=v"(x[9]), "=v"(x[10]), "=v"(x[11]),
          "=v"(x[12]), "=v"(x[13]), "=v"(x[14]), "=v"(x[15]),
          "+v"(voff)
        : "s"(shw4), "s"(pred));
}

// 16 y_true loads: stage order k -> cells k*4+(lane>>4), stride 4 rows = 1360B.
__device__ __forceinline__ void issue_true16(const float* __restrict__ tru,
                                             unsigned voff, float (&c)[16]) {
    asm volatile(
        "global_load_dword %0, %16, %17\n\t"  "v_add_u32 %16, 1360, %16\n\t"
        "global_load_dword %1, %16, %17\n\t"  "v_add_u32 %16, 1360, %16\n\t"
        "global_load_dword %2, %16, %17\n\t"  "v_add_u32 %16, 1360, %16\n\t"
        "global_load_dword %3, %16, %17\n\t"  "v_add_u32 %16, 1360, %16\n\t"
        "global_load_dword %4, %16, %17\n\t"  "v_add_u32 %16, 1360, %16\n\t"
        "global_load_dword %5, %16, %17\n\t"  "v_add_u32 %16, 1360, %16\n\t"
        "global_load_dword %6, %16, %17\n\t"  "v_add_u32 %16, 1360, %16\n\t"
        "global_load_dword %7, %16, %17\n\t"  "v_add_u32 %16, 1360, %16\n\t"
        "global_load_dword %8, %16, %17\n\t"  "v_add_u32 %16, 1360, %16\n\t"
        "global_load_dword %9, %16, %17\n\t"  "v_add_u32 %16, 1360, %16\n\t"
        "global_load_dword %10, %16, %17\n\t" "v_add_u32 %16, 1360, %16\n\t"
        "global_load_dword %11, %16, %17\n\t" "v_add_u32 %16, 1360, %16\n\t"
        "global_load_dword %12, %16, %17\n\t" "v_add_u32 %16, 1360, %16\n\t"
        "global_load_dword %13, %16, %17\n\t" "v_add_u32 %16, 1360, %16\n\t"
        "global_load_dword %14, %16, %17\n\t" "v_add_u32 %16, 1360, %16\n\t"
        "global_load_dword %15, %16, %17"
        : "=v"(c[0]), "=v"(c[1]), "=v"(c[2]), "=v"(c[3]),
          "=v"(c[4]), "=v"(c[5]), "=v"(c[6]), "=v"(c[7]),
          "=v"(c[8]), "=v"(c[9]), "=v"(c[10]), "=v"(c[11]),
          "=v"(c[12]), "=v"(c[13]), "=v"(c[14]), "=v"(c[15]),
          "+v"(voff)
        : "s"(tru));
}

// scatter staged y_true regs into the wave-private LDS tile (stride 17 = bank-free)
__device__ __forceinline__ void write_cls(float (*S)[17], int lane, const float (&r)[16]) {
#pragma unroll
    for (int k = 0; k < 16; k++)
        S[k * 4 + (lane >> 4)][lane & 15] = r[k];
}

// Phase Q: issue chunk Q+1 (32 loads), wait vmcnt(32) => chunk Q landed (it is
// the older cohort; vmcnt retires in issue order), sched_barrier (rule #18:
// stops hoisting of reg-only consumers past the asm wait), then stage+consume.
template<int Q>
__device__ __forceinline__ void class_phase_asm(
    const float* __restrict__ pred, const float* __restrict__ tru,
    float (*S)[17], int lane, unsigned pboff4, unsigned shw4, unsigned tbase4,
    float (&xcur)[16], float (&xnext)[16],
    float (&ccur)[16], float (&cnext)[16], float& cls)
{
    if constexpr (Q < 4) {
        issue_pred16(pred, pboff4 + (unsigned)(5 + 16 * (Q + 1)) * shw4, shw4, xnext);
        issue_true16(tru, tbase4 + (unsigned)(5 + 16 * (Q + 1)) * 4u, cnext);
        asm volatile("s_waitcnt vmcnt(32)");
    } else {
        asm volatile("s_waitcnt vmcnt(0)");
    }
    __builtin_amdgcn_sched_barrier(0);
    write_cls(S, lane, ccur);
#pragma unroll
    for (int c = 0; c < 16; c++) {
        float t = S[lane][c];              // stride-17: 2-way bank alias = free
        cls += softplusf(xcur[c]) - t * xcur[c];
    }
    __builtin_amdgcn_sched_barrier(0);
    (void)cnext;
}

// __launch_bounds__(256,4): VGPR cap 128 — needed for the 64 asm-pinned buffer
// regs (xA,xB,cA,cB). R7 proved raising the bound shrinks schedule depth.
__global__ __launch_bounds__(BLOCK, 4) void yolo_loss_main(
    const float* __restrict__ p0, const float* __restrict__ p1, const float* __restrict__ p2,
    const float* __restrict__ t0, const float* __restrict__ t1, const float* __restrict__ t2,
    const float* __restrict__ tgt, float* __restrict__ partials)
{
    // per-wave private tiles -> no cross-wave coordination, no barriers
    __shared__ float sh[4][64][17];   // 17408 B

    int blk = blockIdx.x;
    const float* pred;
    const float* tru;
    int layer, g, cells, bbase;
    if (blk < NB0)            { layer = 0; pred = p0; tru = t0; g = 13; cells = 16224;  bbase = 0; }
    else if (blk < NB0 + NB1) { layer = 1; pred = p1; tru = t1; g = 26; cells = 64896;  bbase = NB0; }
    else                      { layer = 2; pred = p2; tru = t2; g = 52; cells = 259584; bbase = NB0 + NB1; }

    int tid = threadIdx.x;
    int lane = tid & 63;
    int wv = tid >> 6;
    int cell0 = (blk - bbase) * BLOCK + wv * 64;   // this wave's first cell
    int nv = cells - cell0;                        // valid cells for this wave
    int hw = g * g;
    float acc = 0.f;

    if (nv >= 64) {                                // full wave (all but 1 in grid)
        float (*S)[17] = sh[wv];
        const float* tw = tru + (size_t)cell0 * 85;

        int cidx = cell0 + lane;
        int ij = cidx % hw;
        int a  = (cidx / hw) % 3;
        int b  = cidx / (3 * hw);
        int i  = ij / g;
        int j  = ij - i * g;
        // raw[b][a][i][j][c] = y_pred[b][a*85+c][i][j] (channel stride hw, coalesced)
        int pbo = ((b * 3 + a) * 85) * hw + ij;
        const float* pb = pred + (size_t)pbo;

        unsigned shw4   = (unsigned)hw * 4u;
        unsigned pboff4 = (unsigned)pbo * 4u;
        unsigned tbase4 = (unsigned)((cell0 + (lane >> 4)) * 85 + (lane & 15)) * 4u;

        float xA[16], xB[16], cA[16], cB[16];

        // issue chunk 0 FIRST: oldest in queue -> retires under head compute for
        // free even though the compiler's head-load waits drain the counter.
        issue_pred16(pred, pboff4 + 5u * shw4, shw4, xA);
        issue_true16(tru, tbase4 + 20u, cA);

        // ---- head (compiler code): stage ch 0..4, xy/wh/conf/IoU ----
        float hreg[5];
#pragma unroll
        for (int k = 0; k < 5; k++) {
            int f = k * 64 + lane;
            int cell = f / 5;
            int ch = f - cell * 5;
            hreg[k] = tw[cell * 85 + ch];
        }
#pragma unroll
        for (int k = 0; k < 5; k++) {
            int f = k * 64 + lane;
            int cell = f / 5;
            int ch = f - cell * 5;
            S[cell][ch] = hreg[k];
        }

        float y0 = S[lane][0], y1 = S[lane][1], y2 = S[lane][2], y3 = S[lane][3];
        float mask = S[lane][4];

        float r0 = pb[0];
        float r1 = pb[hw];
        float r2 = pb[2 * hw];
        float r3 = pb[3 * hw];
        float r4 = pb[4 * hw];

        float gf = (float)g, gx = (float)j, gy = (float)i;
        float aw = c_anch[layer * 3 + a][0];
        float ah = c_anch[layer * 3 + a][1];

        // xy loss: bce(sigmoid(r), t) = softplus(r) - t*r
        float true_x = y0 * gf - gx;
        float true_y = y1 * gf - gy;
        float ls = 2.f - y2 * y3;   // loss_scale
        float lxy = (softplusf(r0) - true_x * r0) + (softplusf(r1) - true_y * r1);
        acc += mask * ls * lxy;

        // wh loss
        float tw_ = __logf(y2 * (416.f / aw));
        float th_ = __logf(y3 * (416.f / ah));
        float dw = r2 - tw_, dh = r3 - th_;
        acc += mask * ls * 0.5f * (dw * dw + dh * dh);

        // conf bce
        float cbce = softplusf(r4) - mask * r4;

        // IoU vs 20 targets -> neg mask (tgt wave-uniform, L1-resident)
        float sx = sigmoidf(r0);
        float sy = sigmoidf(r1);
        float bx = __fdividef(sx + gx, gf);
        float by = __fdividef(sy + gy, gf);
        float bw = __expf(r2) * aw * (1.f / 416.f);
        float bh = __expf(r3) * ah * (1.f / 416.f);
        float a1 = bw * bh;
        float b1minx = bx - 0.5f * bw, b1maxx = bx + 0.5f * bw;
        float b1miny = by - 0.5f * bh, b1maxy = by + 0.5f * bh;

        const float* tg = tgt + b * 20 * 5;
        float best = 0.f;
#pragma unroll 5
        for (int k = 0; k < 20; k++) {
            f4a t = *reinterpret_cast<const f4a*>(tg + k * 5);  // tx,ty,tw,th
            float hw2 = 0.5f * t.z, hh2 = 0.5f * t.w;
            float iw = fminf(b1maxx, t.x + hw2) - fmaxf(b1minx, t.x - hw2);
            float ih = fminf(b1maxy, t.y + hh2) - fmaxf(b1miny, t.y - hh2);
            iw = fmaxf(iw, 0.f);
            ih = fmaxf(ih, 0.f);
            float inter = iw * ih;
            float iou = __fdividef(inter, a1 + t.z * t.w - inter);
            best = fmaxf(best, iou);
        }
        float neg = (best < 0.5f) ? 1.f : 0.f;
        acc += mask * cbce + (1.f - mask) * neg * cbce;

        // ---- class chunks: compiler-proof asm pipeline, 32 loads always in flight ----
        float cls = 0.f;
        class_phase_asm<0>(pred, tru, S, lane, pboff4, shw4, tbase4, xA, xB, cA, cB, cls);
        class_phase_asm<1>(pred, tru, S, lane, pboff4, shw4, tbase4, xB, xA, cB, cA, cls);
        class_phase_asm<2>(pred, tru, S, lane, pboff4, shw4, tbase4, xA, xB, cA, cB, cls);
        class_phase_asm<3>(pred, tru, S, lane, pboff4, shw4, tbase4, xB, xA, cB, cA, cls);
        class_phase_asm<4>(pred, tru, S, lane, pboff4, shw4, tbase4, xA, xB, cA, cB, cls);

        acc += mask * cls;
    } else if (nv > 0 && lane < nv) {
        // fallback: exactly ONE wave in the whole grid (L0 blk63 wv1, nv=32).
        // Simple direct-gather path, no asm, no LDS, perf-irrelevant.
        int cidx = cell0 + lane;
        int ij = cidx % hw;
        int a  = (cidx / hw) % 3;
        int b  = cidx / (3 * hw);
        int i  = ij / g;
        int j  = ij - i * g;
        const float* pb = pred + (size_t)(((b * 3 + a) * 85) * hw + ij);
        const float* tb = tru + (size_t)cidx * 85;

        float y0 = tb[0], y1 = tb[1], y2 = tb[2], y3 = tb[3], mask = tb[4];
        float r0 = pb[0], r1 = pb[hw], r2 = pb[2 * hw], r3 = pb[3 * hw], r4 = pb[4 * hw];

        float gf = (float)g, gx = (float)j, gy = (float)i;
        float aw = c_anch[layer * 3 + a][0];
        float ah = c_anch[layer * 3 + a][1];

        float true_x = y0 * gf - gx;
        float true_y = y1 * gf - gy;
        float ls = 2.f - y2 * y3;
        float lxy = (softplusf(r0) - true_x * r0) + (softplusf(r1) - true_y * r1);
        acc += mask * ls * lxy;

        float tw_ = __logf(y2 * (416.f / aw));
        float th_ = __logf(y3 * (416.f / ah));
        float dw = r2 - tw_, dh = r3 - th_;
        acc += mask * ls * 0.5f * (dw * dw + dh * dh);

        float cbce = softplusf(r4) - mask * r4;

        float sx = sigmoidf(r0);
        float sy = sigmoidf(r1);
        float bx = __fdividef(sx + gx, gf);
        float by = __fdividef(sy + gy, gf);
        float bw = __expf(r2) * aw * (1.f / 416.f);
        float bh = __expf(r3) * ah * (1.f / 416.f);
        float a1 = bw * bh;
        float b1minx = bx - 0.5f * bw, b1maxx = bx + 0.5f * bw;
        float b1miny = by - 0.5f * bh, b1maxy = by + 0.5f * bh;

        const float* tg = tgt + b * 20 * 5;
        float best = 0.f;
        for (int k = 0; k < 20; k++) {
            f4a t = *reinterpret_cast<const f4a*>(tg + k * 5);
            float hw2 = 0.5f * t.z, hh2 = 0.5f * t.w;
            float iw = fminf(b1maxx, t.x + hw2) - fmaxf(b1minx, t.x - hw2);
            float ih = fminf(b1maxy, t.y + hh2) - fmaxf(b1miny, t.y - hh2);
            iw = fmaxf(iw, 0.f);
            ih = fmaxf(ih, 0.f);
            float inter = iw * ih;
            float iou = __fdividef(inter, a1 + t.z * t.w - inter);
            best = fmaxf(best, iou);
        }
        float neg = (best < 0.5f) ? 1.f : 0.f;
        acc += mask * cbce + (1.f - mask) * neg * cbce;

        float cls = 0.f;
        for (int c = 0; c < 80; c++) {
            float x = pb[(size_t)(5 + c) * hw];
            float t = tb[5 + c];
            cls += softplusf(x) - t * x;
        }
        acc += mask * cls;
    }

    // ---- block reduction: wave shuffle then LDS (only barrier in the kernel) ----
    for (int off = 32; off > 0; off >>= 1)
        acc += __shfl_down(acc, off, 64);
    __shared__ float shr[BLOCK / 64];
    if ((threadIdx.x & 63) == 0)
        shr[threadIdx.x >> 6] = acc;
    __syncthreads();
    if (threadIdx.x == 0) {
        float s = 0.f;
        for (int w = 0; w < BLOCK / 64; w++) s += shr[w];
        partials[blockIdx.x] = s;
    }
}

__global__ __launch_bounds__(BLOCK) void yolo_loss_reduce(
    const float* __restrict__ partials, float* __restrict__ out)
{
    float s = 0.f;
    for (int i = threadIdx.x; i < NBLOCKS; i += BLOCK)
        s += partials[i];
    for (int off = 32; off > 0; off >>= 1)
        s += __shfl_down(s, off, 64);
    __shared__ float sh[BLOCK / 64];
    if ((threadIdx.x & 63) == 0)
        sh[threadIdx.x >> 6] = s;
    __syncthreads();
    if (threadIdx.x == 0) {
        float tot = 0.f;
        for (int wv = 0; wv < BLOCK / 64; wv++) tot += sh[wv];
        out[0] = tot;
    }
}

extern "C" void kernel_launch(void* const* d_in, const int* in_sizes, int n_in,
                              void* d_out, int out_size, void* d_ws, size_t ws_size,
                              hipStream_t stream) {
    // setup_inputs() dict order is INTERLEAVED:
    //   d_in[0]=y_pred0, d_in[1]=y_true0, d_in[2]=y_pred1, d_in[3]=y_true1,
    //   d_in[4]=y_pred2, d_in[5]=y_true2, d_in[6]=target
    const float* p0  = (const float*)d_in[0];
    const float* t0  = (const float*)d_in[1];
    const float* p1  = (const float*)d_in[2];
    const float* t1  = (const float*)d_in[3];
    const float* p2  = (const float*)d_in[4];
    const float* t2  = (const float*)d_in[5];
    const float* tgt = (const float*)d_in[6];
    float* partials  = (float*)d_ws;   // NBLOCKS floats; every slot written each call

    yolo_loss_main<<<NBLOCKS, BLOCK, 0, stream>>>(p0, p1, p2, t0, t1, t2, tgt, partials);
    yolo_loss_reduce<<<1, BLOCK, 0, stream>>>(partials, (float*)d_out);
}